// Round 1
// baseline (104.330 us; speedup 1.0000x reference)
//
#include <hip/hip_runtime.h>
#include <hip/hip_bf16.h>

#define BB 16
#define TT 2048
#define CC 68
#define HH 64
#define PP 40   // P row stride in shorts (32 kv + 8 pad; 80 B rows, 16B-aligned)

typedef short short8 __attribute__((ext_vector_type(8)));
typedef float floatx4 __attribute__((ext_vector_type(4)));

static __device__ __forceinline__ unsigned short f2bf(float f) {
    union { float f; unsigned u; } v; v.f = f;
    unsigned r = v.u + 0x7fffu + ((v.u >> 16) & 1u);
    return (unsigned short)(r >> 16);
}
static __device__ __forceinline__ unsigned pk2(float a, float b) {
    unsigned ua = __builtin_bit_cast(unsigned, a) + 0x8000u;
    unsigned ub = __builtin_bit_cast(unsigned, b) + 0x8000u;
    return (ua >> 16) | (ub & 0xffff0000u);
}

#define GLD16(gsrc, ldsbase)                                                        \
    __builtin_amdgcn_global_load_lds(                                               \
        (const __attribute__((address_space(1))) unsigned int*)(gsrc),              \
        (__attribute__((address_space(3))) unsigned int*)(ldsbase), 16, 0, 0)

#define WAITV4 asm volatile("s_waitcnt vmcnt(4)" ::: "memory")
#define WAITV0 asm volatile("s_waitcnt vmcnt(0)" ::: "memory")
#define BAR    asm volatile("s_barrier" ::: "memory")

// ---------------- Kernel 0: W prep ----------------
// Wt[n][c]: n in [0,192) = K|Q|V output column, c in [0,96) zero-padded.
// Q columns pre-scaled by 0.125*log2(e) so attention uses exp2 directly.
__global__ __launch_bounds__(256) void prep_w(
        const float* __restrict__ Wk, const float* __restrict__ Wq,
        const float* __restrict__ Wv, unsigned short* __restrict__ Wt) {
    int idx = blockIdx.x * 256 + threadIdx.x;
    if (idx >= 192 * 96) return;
    int n = idx / 96, c = idx - n * 96;
    float v = 0.f;
    if (c < CC) {
        if (n < 64)       v = Wk[c * 64 + n];
        else if (n < 128) v = Wq[c * 64 + (n - 64)] * 0.18033688011112042f; // 0.125*log2e
        else              v = Wv[c * 64 + (n - 128)];
    }
    Wt[idx] = f2bf(v);
}

// ---------------- Kernel 1: QKV projection, LDS-free ----------------
// 512 blocks x 256 thr; id = rowblk*16 + b (XCD = b%8, matches attn).
// Wave handles 16 x-rows; W B-frags from L2-hot Wt with 2-deep prefetch.
__global__ __launch_bounds__(256) void qkv_kernel(
        const float* __restrict__ x, const unsigned short* __restrict__ Wt,
        unsigned short* __restrict__ Qb, unsigned short* __restrict__ Kb,
        unsigned short* __restrict__ Vt) {
    int tid = threadIdx.x;
    int wave = tid >> 6, lane = tid & 63, quad = lane >> 4, l15 = lane & 15;
    int id = blockIdx.x;
    int b = id & 15, rowblk = id >> 4;
    size_t row0 = (size_t)b * TT + rowblk * 64;
    int t0 = rowblk * 64;
    size_t myrow = row0 + wave * 16 + l15;
    const float* xr = x + myrow * CC;

    // A-fragments: x[myrow][c], c = cs*32 + quad*8 .. +7 (c>=68 -> 0)
    short8 a[3];
    union { short8 s8; unsigned u[4]; } t;
    #pragma unroll
    for (int cs = 0; cs < 2; ++cs) {
        float4 f0 = *(const float4*)(xr + cs * 32 + quad * 8);
        float4 f1 = *(const float4*)(xr + cs * 32 + quad * 8 + 4);
        t.u[0] = pk2(f0.x, f0.y); t.u[1] = pk2(f0.z, f0.w);
        t.u[2] = pk2(f1.x, f1.y); t.u[3] = pk2(f1.z, f1.w);
        a[cs] = t.s8;
    }
    {
        t.u[0] = 0; t.u[1] = 0; t.u[2] = 0; t.u[3] = 0;
        if (quad == 0) {
            float4 f = *(const float4*)(xr + 64);
            t.u[0] = pk2(f.x, f.y); t.u[1] = pk2(f.z, f.w);
        }
        a[2] = t.s8;
    }

    auto loadW = [&](short8 (&w)[3], int nt) {
        #pragma unroll
        for (int cs = 0; cs < 3; ++cs)
            w[cs] = *(const short8*)&Wt[(nt * 16 + l15) * 96 + cs * 32 + quad * 8];
    };

    short8 wf[3][3];
    loadW(wf[0], 0);
    loadW(wf[1], 1);
    #pragma unroll
    for (int nt = 0; nt < 12; ++nt) {
        if (nt + 2 < 12) loadW(wf[(nt + 2) % 3], nt + 2);
        floatx4 acc = (floatx4){0.f, 0.f, 0.f, 0.f};
        #pragma unroll
        for (int cs = 0; cs < 3; ++cs)
            acc = __builtin_amdgcn_mfma_f32_16x16x32_bf16(a[cs], wf[nt % 3][cs], acc, 0, 0, 0);

        if (nt < 8) {
            unsigned short* dst = (nt < 4) ? Kb : Qb;
            int h = (nt & 3) * 16 + l15;
            #pragma unroll
            for (int r = 0; r < 4; ++r)
                dst[(row0 + wave * 16 + quad * 4 + r) * 64 + h] = f2bf(acc[r]);
        } else {
            int h = (nt - 8) * 16 + l15;
            int tt = t0 + wave * 16 + quad * 4;
            uint2 v2; v2.x = pk2(acc[0], acc[1]); v2.y = pk2(acc[2], acc[3]);
            *(uint2*)&Vt[((size_t)(b * 64 + h)) * TT + tt] = v2;
        }
    }
}

// ---------------- Kernel 2: flash attention, shared staging, 1 barrier/iter ----------------
// 256 WGs x 512 thr (8 waves). id = qblk*16 + b. Wave = (half = w>>2 over kv,
// qh = w&3 over 32-q strips of a 128-q tile). Per half: wave qh=0 stages K,
// qh=1 stages V (global_load_lds, triple-buffered). Producers wait vmcnt(4) --
// DMA queue never drains; ONE s_barrier per iter.
__global__ __launch_bounds__(512, 2) void attn_kernel(
        const unsigned short* __restrict__ Qb,
        const unsigned short* __restrict__ Kb,
        const unsigned short* __restrict__ Vt,
        float* __restrict__ out) {
    __shared__ union {
        unsigned char stg[2][3][8192];   // [half][buf][ K 4KB | V 4KB ]
        float accL[128][66];             // combine overlay
    } u;
    __shared__ unsigned short Ps[8][32 * PP];
    __shared__ float lL[2][128];

    int tid = threadIdx.x;
    int wave = tid >> 6, lane = tid & 63, quad = lane >> 4, l15 = lane & 15;
    int half = wave >> 2, qh = wave & 3;
    int id = blockIdx.x;
    int b = id & 15, qblk = id >> 4;          // XCD = b%8 (matches qkv writes)
    int q0 = qblk * 128 + qh * 32;
    int kbase = half * 1024;
    unsigned short* ps = Ps[wave];

    // Q fragments (B-operand of S^T): Q[q=qs*16+l15][h=kh*32+quad*8+j]
    short8 qf[2][2];
    #pragma unroll
    for (int qs = 0; qs < 2; ++qs)
        #pragma unroll
        for (int kh = 0; kh < 2; ++kh)
            qf[qs][kh] = *(const short8*)&Qb[((size_t)(b * TT + q0 + qs * 16 + l15)) * 64
                                             + kh * 32 + quad * 8];

    floatx4 acc[2][4];
    float lpart[2] = {0.f, 0.f};
    #pragma unroll
    for (int qs = 0; qs < 2; ++qs)
        #pragma unroll
        for (int hb = 0; hb < 4; ++hb) acc[qs][hb] = (floatx4){0.f, 0.f, 0.f, 0.f};

    // stage tile `it` into buf p. K swizzle c'=c^(kv&7); V swizzle c'=c^((h>>1)&3).
    auto stage = [&](int it, int p) {
        int kt = kbase + it * 32;
        if (qh == 0) {
            unsigned char* base = u.stg[half][p];
            #pragma unroll
            for (int i = 0; i < 4; ++i) {
                int ci = i * 64 + lane;
                int kv = ci >> 3, cp = ci & 7, c = cp ^ (kv & 7);
                GLD16(Kb + ((size_t)(b * TT + kt + kv) * 64 + c * 8), base + i * 1024);
            }
        } else if (qh == 1) {
            unsigned char* base = u.stg[half][p] + 4096;
            #pragma unroll
            for (int i = 0; i < 4; ++i) {
                int ci = i * 64 + lane;
                int h = ci >> 2, cp = ci & 3, c = cp ^ ((h >> 1) & 3);
                GLD16(Vt + ((size_t)(b * 64 + h) * TT + kt + c * 8), base + i * 1024);
            }
        }
    };

    auto compute = [&](int p) {
        const unsigned char* Kbuf = u.stg[half][p];
        const unsigned char* Vbuf = Kbuf + 4096;

        short8 kf[2][2], vf[4];
        #pragma unroll
        for (int ks = 0; ks < 2; ++ks)
            #pragma unroll
            for (int kh = 0; kh < 2; ++kh) {
                int cp = (kh * 4 + quad) ^ (l15 & 7);
                kf[ks][kh] = *(const short8*)(Kbuf + (ks * 16 + l15) * 128 + cp * 16);
            }
        #pragma unroll
        for (int hb = 0; hb < 4; ++hb) {
            int cp = quad ^ ((l15 >> 1) & 3);
            vf[hb] = *(const short8*)(Vbuf + (hb * 16 + l15) * 64 + cp * 16);
        }

        floatx4 s[2][2];
        #pragma unroll
        for (int qs = 0; qs < 2; ++qs)
            #pragma unroll
            for (int ks = 0; ks < 2; ++ks) {
                floatx4 z = (floatx4){0.f, 0.f, 0.f, 0.f};
                z = __builtin_amdgcn_mfma_f32_16x16x32_bf16(kf[ks][0], qf[qs][0], z, 0, 0, 0);
                z = __builtin_amdgcn_mfma_f32_16x16x32_bf16(kf[ks][1], qf[qs][1], z, 0, 0, 0);
                s[qs][ks] = z;
            }

        #pragma unroll
        for (int qs = 0; qs < 2; ++qs) {
            float lp = 0.f;
            #pragma unroll
            for (int ks = 0; ks < 2; ++ks) {
                float e0 = __builtin_amdgcn_exp2f(s[qs][ks][0]);
                float e1 = __builtin_amdgcn_exp2f(s[qs][ks][1]);
                float e2 = __builtin_amdgcn_exp2f(s[qs][ks][2]);
                float e3 = __builtin_amdgcn_exp2f(s[qs][ks][3]);
                lp += (e0 + e1) + (e2 + e3);
                uint2 w; w.x = pk2(e0, e1); w.y = pk2(e2, e3);
                *(uint2*)&ps[(qs * 16 + l15) * PP + ks * 16 + quad * 4] = w;
            }
            lpart[qs] += lp;
        }

        short8 pf[2];
        #pragma unroll
        for (int qs = 0; qs < 2; ++qs)
            pf[qs] = *(const short8*)&ps[(qs * 16 + l15) * PP + quad * 8];
        #pragma unroll
        for (int qs = 0; qs < 2; ++qs)
            #pragma unroll
            for (int hb = 0; hb < 4; ++hb)
                acc[qs][hb] = __builtin_amdgcn_mfma_f32_16x16x32_bf16(pf[qs], vf[hb], acc[qs][hb], 0, 0, 0);
    };

    stage(0, 0);
    stage(1, 1);
    for (int it = 0; it < 32; ++it) {
        if (qh < 2) {
            if (it < 31) { WAITV4; } else { WAITV0; }   // tile `it` landed, it+1 in flight
        }
        BAR;                                            // tile visible WG-wide
        if (it + 2 < 32) stage(it + 2, (it + 2) % 3);   // overwrites buf read at it-1 (done)
        compute(it % 3);
    }

    // l: sum across quads
    #pragma unroll
    for (int qs = 0; qs < 2; ++qs) {
        float v = lpart[qs];
        v += __shfl_xor(v, 16);
        v += __shfl_xor(v, 32);
        lpart[qs] = v;
    }
    if (quad == 0) {
        lL[half][qh * 32 + l15]      = lpart[0];
        lL[half][qh * 32 + 16 + l15] = lpart[1];
    }
    __syncthreads();   // full drain OK here (epilogue); lL visible

    if (half == 1) {
        #pragma unroll
        for (int qs = 0; qs < 2; ++qs)
            #pragma unroll
            for (int hb = 0; hb < 4; ++hb)
                #pragma unroll
                for (int r = 0; r < 4; ++r)
                    u.accL[qh * 32 + qs * 16 + quad * 4 + r][hb * 16 + l15] = acc[qs][hb][r];
    }
    __syncthreads();

    if (half == 0) {
        #pragma unroll
        for (int qs = 0; qs < 2; ++qs) {
            float rl[4];
            #pragma unroll
            for (int r = 0; r < 4; ++r) {
                int qw = qh * 32 + qs * 16 + quad * 4 + r;
                rl[r] = 1.0f / (lL[0][qw] + lL[1][qw]);
            }
            #pragma unroll
            for (int hb = 0; hb < 4; ++hb)
                #pragma unroll
                for (int r = 0; r < 4; ++r) {
                    int qw = qh * 32 + qs * 16 + quad * 4 + r;
                    float tot = acc[qs][hb][r] + u.accL[qw][hb * 16 + l15];
                    out[((size_t)(b * TT + qblk * 128 + qw)) * 64 + hb * 16 + l15] = tot * rl[r];
                }
        }
    }
}

extern "C" void kernel_launch(void* const* d_in, const int* in_sizes, int n_in,
                              void* d_out, int out_size, void* d_ws, size_t ws_size,
                              hipStream_t stream) {
    const float* x  = (const float*)d_in[0];
    const float* Wk = (const float*)d_in[1];
    const float* Wq = (const float*)d_in[2];
    const float* Wv = (const float*)d_in[3];

    unsigned short* Qb = (unsigned short*)d_ws;
    unsigned short* Kb = Qb + (size_t)BB * TT * HH;
    unsigned short* Vt = Kb + (size_t)BB * TT * HH;
    unsigned short* Wt = Vt + (size_t)BB * TT * HH;
    float* out = (float*)d_out;

    prep_w<<<dim3(72), dim3(256), 0, stream>>>(Wk, Wq, Wv, Wt);
    qkv_kernel<<<dim3(BB * TT / 64), dim3(256), 0, stream>>>(x, Wt, Qb, Kb, Vt);
    attn_kernel<<<dim3(BB * (TT / 128)), dim3(512), 0, stream>>>(Qb, Kb, Vt, out);
}

// Round 2
// 101.597 us; speedup vs baseline: 1.0269x; 1.0269x over previous
//
#include <hip/hip_runtime.h>
#include <hip/hip_bf16.h>

#define BB 16
#define TT 2048
#define CC 68
#define HH 64

typedef short short8 __attribute__((ext_vector_type(8)));
typedef float floatx4 __attribute__((ext_vector_type(4)));

static __device__ __forceinline__ unsigned short f2bf(float f) {
    union { float f; unsigned u; } v; v.f = f;
    unsigned r = v.u + 0x7fffu + ((v.u >> 16) & 1u);
    return (unsigned short)(r >> 16);
}
static __device__ __forceinline__ unsigned pk2(float a, float b) {
    unsigned ua = __builtin_bit_cast(unsigned, a) + 0x8000u;
    unsigned ub = __builtin_bit_cast(unsigned, b) + 0x8000u;
    return (ua >> 16) | (ub & 0xffff0000u);
}
// packed f32->bf16 (RNE), src0 -> low half
static __device__ __forceinline__ unsigned cvtpk(float a, float b) {
    unsigned r;
    asm("v_cvt_pk_bf16_f32 %0, %1, %2" : "=v"(r) : "v"(a), "v"(b));
    return r;
}

#define GLD16(gsrc, ldsbase)                                                        \
    __builtin_amdgcn_global_load_lds(                                               \
        (const __attribute__((address_space(1))) unsigned int*)(gsrc),              \
        (__attribute__((address_space(3))) unsigned int*)(ldsbase), 16, 0, 0)

#define WAITV4 asm volatile("s_waitcnt vmcnt(4)" ::: "memory")
#define WAITV0 asm volatile("s_waitcnt vmcnt(0)" ::: "memory")
#define BAR    asm volatile("s_barrier" ::: "memory")

// ---------------- Kernel 0: W prep ----------------
// Wt[n][c]: n in [0,192) = K|Q|V output column, c in [0,96) zero-padded.
// Q columns pre-scaled by 0.125*log2(e) so attention uses exp2 directly.
__global__ __launch_bounds__(256) void prep_w(
        const float* __restrict__ Wk, const float* __restrict__ Wq,
        const float* __restrict__ Wv, unsigned short* __restrict__ Wt) {
    int idx = blockIdx.x * 256 + threadIdx.x;
    if (idx >= 192 * 96) return;
    int n = idx / 96, c = idx - n * 96;
    float v = 0.f;
    if (c < CC) {
        if (n < 64)       v = Wk[c * 64 + n];
        else if (n < 128) v = Wq[c * 64 + (n - 64)] * 0.18033688011112042f; // 0.125*log2e
        else              v = Wv[c * 64 + (n - 128)];
    }
    Wt[idx] = f2bf(v);
}

// ---------------- Kernel 1: QKV projection, LDS-free ----------------
__global__ __launch_bounds__(256) void qkv_kernel(
        const float* __restrict__ x, const unsigned short* __restrict__ Wt,
        unsigned short* __restrict__ Qb, unsigned short* __restrict__ Kb,
        unsigned short* __restrict__ Vt) {
    int tid = threadIdx.x;
    int wave = tid >> 6, lane = tid & 63, quad = lane >> 4, l15 = lane & 15;
    int id = blockIdx.x;
    int b = id & 15, rowblk = id >> 4;
    size_t row0 = (size_t)b * TT + rowblk * 64;
    int t0 = rowblk * 64;
    size_t myrow = row0 + wave * 16 + l15;
    const float* xr = x + myrow * CC;

    // A-fragments: x[myrow][c], c = cs*32 + quad*8 .. +7 (c>=68 -> 0)
    short8 a[3];
    union { short8 s8; unsigned u[4]; } t;
    #pragma unroll
    for (int cs = 0; cs < 2; ++cs) {
        float4 f0 = *(const float4*)(xr + cs * 32 + quad * 8);
        float4 f1 = *(const float4*)(xr + cs * 32 + quad * 8 + 4);
        t.u[0] = pk2(f0.x, f0.y); t.u[1] = pk2(f0.z, f0.w);
        t.u[2] = pk2(f1.x, f1.y); t.u[3] = pk2(f1.z, f1.w);
        a[cs] = t.s8;
    }
    {
        t.u[0] = 0; t.u[1] = 0; t.u[2] = 0; t.u[3] = 0;
        if (quad == 0) {
            float4 f = *(const float4*)(xr + 64);
            t.u[0] = pk2(f.x, f.y); t.u[1] = pk2(f.z, f.w);
        }
        a[2] = t.s8;
    }

    auto loadW = [&](short8 (&w)[3], int nt) {
        #pragma unroll
        for (int cs = 0; cs < 3; ++cs)
            w[cs] = *(const short8*)&Wt[(nt * 16 + l15) * 96 + cs * 32 + quad * 8];
    };

    short8 wf[3][3];
    loadW(wf[0], 0);
    loadW(wf[1], 1);
    #pragma unroll
    for (int nt = 0; nt < 12; ++nt) {
        if (nt + 2 < 12) loadW(wf[(nt + 2) % 3], nt + 2);
        floatx4 acc = (floatx4){0.f, 0.f, 0.f, 0.f};
        #pragma unroll
        for (int cs = 0; cs < 3; ++cs)
            acc = __builtin_amdgcn_mfma_f32_16x16x32_bf16(a[cs], wf[nt % 3][cs], acc, 0, 0, 0);

        if (nt < 8) {
            unsigned short* dst = (nt < 4) ? Kb : Qb;
            int h = (nt & 3) * 16 + l15;
            #pragma unroll
            for (int r = 0; r < 4; ++r)
                dst[(row0 + wave * 16 + quad * 4 + r) * 64 + h] = f2bf(acc[r]);
        } else {
            int h = (nt - 8) * 16 + l15;
            int tt = t0 + wave * 16 + quad * 4;
            uint2 v2; v2.x = pk2(acc[0], acc[1]); v2.y = pk2(acc[2], acc[3]);
            *(uint2*)&Vt[((size_t)(b * 64 + h)) * TT + tt] = v2;
        }
    }
}

// ---------------- Kernel 2: flash attention ----------------
// 256 WGs x 512 thr (8 waves). Wave = (half = w>>2 over kv, qh = w&3 over 32-q
// strips of a 128-q tile). Producers (qh 0/1) stage K/V via global_load_lds,
// triple-buffered, vmcnt(4) -- DMA queue never drains; ONE s_barrier per iter.
// P redistribution is fully in-register (cvt_pk + permlane32/16_swap): after
// swapped QK^T, lane(quad,l15) holds P[q=l15][k=16ks+4quad+r]; the PV A-frag
// needs P[q=l15][k=8quad+j]. With c[ks][d]=cvtpk(e[2d],e[2d+1]):
//   swap32(c00,c10); swap16(c00,c10)  ->  {P0, P2}
//   swap32(c01,c11); swap16(c01,c11)  ->  {P1, P3}
__global__ __launch_bounds__(512, 2) void attn_kernel(
        const unsigned short* __restrict__ Qb,
        const unsigned short* __restrict__ Kb,
        const unsigned short* __restrict__ Vt,
        float* __restrict__ out) {
    __shared__ union {
        unsigned char stg[2][3][8192];   // [half][buf][ K 4KB | V 4KB ]
        float accL[128][66];             // combine overlay
    } u;
    __shared__ float lL[2][128];

    int tid = threadIdx.x;
    int wave = tid >> 6, lane = tid & 63, quad = lane >> 4, l15 = lane & 15;
    int half = wave >> 2, qh = wave & 3;
    int id = blockIdx.x;
    int b = id & 15, qblk = id >> 4;          // XCD = b%8 (matches qkv writes)
    int q0 = qblk * 128 + qh * 32;
    int kbase = half * 1024;

    // Q fragments (B-operand of S^T): Q[q=qs*16+l15][h=kh*32+quad*8+j]
    short8 qf[2][2];
    #pragma unroll
    for (int qs = 0; qs < 2; ++qs)
        #pragma unroll
        for (int kh = 0; kh < 2; ++kh)
            qf[qs][kh] = *(const short8*)&Qb[((size_t)(b * TT + q0 + qs * 16 + l15)) * 64
                                             + kh * 32 + quad * 8];

    floatx4 acc[2][4];
    float lpart[2] = {0.f, 0.f};
    #pragma unroll
    for (int qs = 0; qs < 2; ++qs)
        #pragma unroll
        for (int hb = 0; hb < 4; ++hb) acc[qs][hb] = (floatx4){0.f, 0.f, 0.f, 0.f};

    // stage tile `it` into buf p. K swizzle c'=c^(kv&7); V swizzle c'=c^((h>>1)&3).
    auto stage = [&](int it, int p) {
        int kt = kbase + it * 32;
        if (qh == 0) {
            unsigned char* base = u.stg[half][p];
            #pragma unroll
            for (int i = 0; i < 4; ++i) {
                int ci = i * 64 + lane;
                int kv = ci >> 3, cp = ci & 7, c = cp ^ (kv & 7);
                GLD16(Kb + ((size_t)(b * TT + kt + kv) * 64 + c * 8), base + i * 1024);
            }
        } else if (qh == 1) {
            unsigned char* base = u.stg[half][p] + 4096;
            #pragma unroll
            for (int i = 0; i < 4; ++i) {
                int ci = i * 64 + lane;
                int h = ci >> 2, cp = ci & 3, c = cp ^ ((h >> 1) & 3);
                GLD16(Vt + ((size_t)(b * 64 + h) * TT + kt + c * 8), base + i * 1024);
            }
        }
    };

    auto compute = [&](int p) {
        const unsigned char* Kbuf = u.stg[half][p];
        const unsigned char* Vbuf = Kbuf + 4096;

        short8 kf[2][2], vf[4];
        #pragma unroll
        for (int ks = 0; ks < 2; ++ks)
            #pragma unroll
            for (int kh = 0; kh < 2; ++kh) {
                int cp = (kh * 4 + quad) ^ (l15 & 7);
                kf[ks][kh] = *(const short8*)(Kbuf + (ks * 16 + l15) * 128 + cp * 16);
            }
        #pragma unroll
        for (int hb = 0; hb < 4; ++hb) {
            int cp = quad ^ ((l15 >> 1) & 3);
            vf[hb] = *(const short8*)(Vbuf + (hb * 16 + l15) * 64 + cp * 16);
        }

        floatx4 s[2][2];
        #pragma unroll
        for (int qs = 0; qs < 2; ++qs)
            #pragma unroll
            for (int ks = 0; ks < 2; ++ks) {
                floatx4 z = (floatx4){0.f, 0.f, 0.f, 0.f};
                z = __builtin_amdgcn_mfma_f32_16x16x32_bf16(kf[ks][0], qf[qs][0], z, 0, 0, 0);
                z = __builtin_amdgcn_mfma_f32_16x16x32_bf16(kf[ks][1], qf[qs][1], z, 0, 0, 0);
                s[qs][ks] = z;
            }

        #pragma unroll
        for (int qs = 0; qs < 2; ++qs) {
            // exp + pack: c[ks][d] = bf16pair(e[2d], e[2d+1]) at k=16ks+4quad+2d
            unsigned c00, c01, c10, c11;
            float lp = 0.f;
            {
                float e0 = __builtin_amdgcn_exp2f(s[qs][0][0]);
                float e1 = __builtin_amdgcn_exp2f(s[qs][0][1]);
                float e2 = __builtin_amdgcn_exp2f(s[qs][0][2]);
                float e3 = __builtin_amdgcn_exp2f(s[qs][0][3]);
                lp += (e0 + e1) + (e2 + e3);
                c00 = cvtpk(e0, e1); c01 = cvtpk(e2, e3);
            }
            {
                float e0 = __builtin_amdgcn_exp2f(s[qs][1][0]);
                float e1 = __builtin_amdgcn_exp2f(s[qs][1][1]);
                float e2 = __builtin_amdgcn_exp2f(s[qs][1][2]);
                float e3 = __builtin_amdgcn_exp2f(s[qs][1][3]);
                lp += (e0 + e1) + (e2 + e3);
                c10 = cvtpk(e0, e1); c11 = cvtpk(e2, e3);
            }
            lpart[qs] += lp;

            // in-register quad redistribution -> PV A-fragment
            asm("v_permlane32_swap_b32 %0, %1" : "+v"(c00), "+v"(c10));
            asm("v_permlane16_swap_b32 %0, %1" : "+v"(c00), "+v"(c10));  // c00=P0 c10=P2
            asm("v_permlane32_swap_b32 %0, %1" : "+v"(c01), "+v"(c11));
            asm("v_permlane16_swap_b32 %0, %1" : "+v"(c01), "+v"(c11));  // c01=P1 c11=P3

            union { short8 s8; unsigned w[4]; } pu;
            pu.w[0] = c00; pu.w[1] = c01; pu.w[2] = c10; pu.w[3] = c11;
            #pragma unroll
            for (int hb = 0; hb < 4; ++hb)
                acc[qs][hb] = __builtin_amdgcn_mfma_f32_16x16x32_bf16(pu.s8, vf[hb], acc[qs][hb], 0, 0, 0);
        }
    };

    stage(0, 0);
    stage(1, 1);
    for (int it = 0; it < 32; ++it) {
        if (qh < 2) {
            if (it < 31) { WAITV4; } else { WAITV0; }   // tile `it` landed, it+1 in flight
        }
        BAR;                                            // tile visible WG-wide
        if (it + 2 < 32) stage(it + 2, (it + 2) % 3);   // overwrites buf read at it-1 (done)
        compute(it % 3);
    }

    // l: sum across quads
    #pragma unroll
    for (int qs = 0; qs < 2; ++qs) {
        float v = lpart[qs];
        v += __shfl_xor(v, 16);
        v += __shfl_xor(v, 32);
        lpart[qs] = v;
    }
    if (quad == 0) {
        lL[half][qh * 32 + l15]      = lpart[0];
        lL[half][qh * 32 + 16 + l15] = lpart[1];
    }
    __syncthreads();   // full drain OK here (epilogue); lL visible

    if (half == 1) {
        #pragma unroll
        for (int qs = 0; qs < 2; ++qs)
            #pragma unroll
            for (int hb = 0; hb < 4; ++hb)
                #pragma unroll
                for (int r = 0; r < 4; ++r)
                    u.accL[qh * 32 + qs * 16 + quad * 4 + r][hb * 16 + l15] = acc[qs][hb][r];
    }
    __syncthreads();

    if (half == 0) {
        #pragma unroll
        for (int qs = 0; qs < 2; ++qs) {
            float rl[4];
            #pragma unroll
            for (int r = 0; r < 4; ++r) {
                int qw = qh * 32 + qs * 16 + quad * 4 + r;
                rl[r] = 1.0f / (lL[0][qw] + lL[1][qw]);
            }
            #pragma unroll
            for (int hb = 0; hb < 4; ++hb)
                #pragma unroll
                for (int r = 0; r < 4; ++r) {
                    int qw = qh * 32 + qs * 16 + quad * 4 + r;
                    float tot = acc[qs][hb][r] + u.accL[qw][hb * 16 + l15];
                    out[((size_t)(b * TT + qblk * 128 + qw)) * 64 + hb * 16 + l15] = tot * rl[r];
                }
        }
    }
}

extern "C" void kernel_launch(void* const* d_in, const int* in_sizes, int n_in,
                              void* d_out, int out_size, void* d_ws, size_t ws_size,
                              hipStream_t stream) {
    const float* x  = (const float*)d_in[0];
    const float* Wk = (const float*)d_in[1];
    const float* Wq = (const float*)d_in[2];
    const float* Wv = (const float*)d_in[3];

    unsigned short* Qb = (unsigned short*)d_ws;
    unsigned short* Kb = Qb + (size_t)BB * TT * HH;
    unsigned short* Vt = Kb + (size_t)BB * TT * HH;
    unsigned short* Wt = Vt + (size_t)BB * TT * HH;
    float* out = (float*)d_out;

    prep_w<<<dim3(72), dim3(256), 0, stream>>>(Wk, Wq, Wv, Wt);
    qkv_kernel<<<dim3(BB * TT / 64), dim3(256), 0, stream>>>(x, Wt, Qb, Kb, Vt);
    attn_kernel<<<dim3(BB * (TT / 128)), dim3(512), 0, stream>>>(Qb, Kb, Vt, out);
}

// Round 3
// 100.778 us; speedup vs baseline: 1.0352x; 1.0081x over previous
//
#include <hip/hip_runtime.h>
#include <hip/hip_bf16.h>

#define BB 16
#define TT 2048
#define CC 68
#define HH 64

typedef short short8 __attribute__((ext_vector_type(8)));
typedef float floatx4 __attribute__((ext_vector_type(4)));

static __device__ __forceinline__ unsigned short f2bf(float f) {
    union { float f; unsigned u; } v; v.f = f;
    unsigned r = v.u + 0x7fffu + ((v.u >> 16) & 1u);
    return (unsigned short)(r >> 16);
}
static __device__ __forceinline__ unsigned pk2(float a, float b) {
    unsigned ua = __builtin_bit_cast(unsigned, a) + 0x8000u;
    unsigned ub = __builtin_bit_cast(unsigned, b) + 0x8000u;
    return (ua >> 16) | (ub & 0xffff0000u);
}
// packed f32->bf16 (RNE), src0 -> low half
static __device__ __forceinline__ unsigned cvtpk(float a, float b) {
    unsigned r;
    asm("v_cvt_pk_bf16_f32 %0, %1, %2" : "=v"(r) : "v"(a), "v"(b));
    return r;
}

#define GLD16(gsrc, ldsbase)                                                        \
    __builtin_amdgcn_global_load_lds(                                               \
        (const __attribute__((address_space(1))) unsigned int*)(gsrc),              \
        (__attribute__((address_space(3))) unsigned int*)(ldsbase), 16, 0, 0)

#define WAITV4 asm volatile("s_waitcnt vmcnt(4)" ::: "memory")
#define WAITV0 asm volatile("s_waitcnt vmcnt(0)" ::: "memory")
#define BAR    asm volatile("s_barrier" ::: "memory")

// ---------------- Kernel 0: W prep ----------------
// Wt[n][c]: n in [0,192) = K|Q|V output column, c in [0,96) zero-padded.
// Q columns pre-scaled by 0.125*log2(e) so attention uses exp2 directly.
__global__ __launch_bounds__(256) void prep_w(
        const float* __restrict__ Wk, const float* __restrict__ Wq,
        const float* __restrict__ Wv, unsigned short* __restrict__ Wt) {
    int idx = blockIdx.x * 256 + threadIdx.x;
    if (idx >= 192 * 96) return;
    int n = idx / 96, c = idx - n * 96;
    float v = 0.f;
    if (c < CC) {
        if (n < 64)       v = Wk[c * 64 + n];
        else if (n < 128) v = Wq[c * 64 + (n - 64)] * 0.18033688011112042f; // 0.125*log2e
        else              v = Wv[c * 64 + (n - 128)];
    }
    Wt[idx] = f2bf(v);
}

// ---------------- Kernel 1: QKV projection, LDS-free ----------------
__global__ __launch_bounds__(256) void qkv_kernel(
        const float* __restrict__ x, const unsigned short* __restrict__ Wt,
        unsigned short* __restrict__ Qb, unsigned short* __restrict__ Kb,
        unsigned short* __restrict__ Vt) {
    int tid = threadIdx.x;
    int wave = tid >> 6, lane = tid & 63, quad = lane >> 4, l15 = lane & 15;
    int id = blockIdx.x;
    int b = id & 15, rowblk = id >> 4;
    size_t row0 = (size_t)b * TT + rowblk * 64;
    int t0 = rowblk * 64;
    size_t myrow = row0 + wave * 16 + l15;
    const float* xr = x + myrow * CC;

    // A-fragments: x[myrow][c], c = cs*32 + quad*8 .. +7 (c>=68 -> 0)
    short8 a[3];
    union { short8 s8; unsigned u[4]; } t;
    #pragma unroll
    for (int cs = 0; cs < 2; ++cs) {
        float4 f0 = *(const float4*)(xr + cs * 32 + quad * 8);
        float4 f1 = *(const float4*)(xr + cs * 32 + quad * 8 + 4);
        t.u[0] = pk2(f0.x, f0.y); t.u[1] = pk2(f0.z, f0.w);
        t.u[2] = pk2(f1.x, f1.y); t.u[3] = pk2(f1.z, f1.w);
        a[cs] = t.s8;
    }
    {
        t.u[0] = 0; t.u[1] = 0; t.u[2] = 0; t.u[3] = 0;
        if (quad == 0) {
            float4 f = *(const float4*)(xr + 64);
            t.u[0] = pk2(f.x, f.y); t.u[1] = pk2(f.z, f.w);
        }
        a[2] = t.s8;
    }

    auto loadW = [&](short8 (&w)[3], int nt) {
        #pragma unroll
        for (int cs = 0; cs < 3; ++cs)
            w[cs] = *(const short8*)&Wt[(nt * 16 + l15) * 96 + cs * 32 + quad * 8];
    };

    short8 wf[3][3];
    loadW(wf[0], 0);
    loadW(wf[1], 1);
    #pragma unroll
    for (int nt = 0; nt < 12; ++nt) {
        if (nt + 2 < 12) loadW(wf[(nt + 2) % 3], nt + 2);
        floatx4 acc = (floatx4){0.f, 0.f, 0.f, 0.f};
        #pragma unroll
        for (int cs = 0; cs < 3; ++cs)
            acc = __builtin_amdgcn_mfma_f32_16x16x32_bf16(a[cs], wf[nt % 3][cs], acc, 0, 0, 0);

        if (nt < 8) {
            unsigned short* dst = (nt < 4) ? Kb : Qb;
            int h = (nt & 3) * 16 + l15;
            #pragma unroll
            for (int r = 0; r < 4; ++r)
                dst[(row0 + wave * 16 + quad * 4 + r) * 64 + h] = f2bf(acc[r]);
        } else {
            int h = (nt - 8) * 16 + l15;
            int tt = t0 + wave * 16 + quad * 4;
            uint2 v2; v2.x = pk2(acc[0], acc[1]); v2.y = pk2(acc[2], acc[3]);
            *(uint2*)&Vt[((size_t)(b * 64 + h)) * TT + tt] = v2;
        }
    }
}

// ---------------- Kernel 2: flash attention, 64-q tiles, 2 WG/CU ----------------
// 512 WGs x 512 thr (8 waves), 2 WG/CU -> 4 waves/SIMD, two independent barrier
// domains per CU overlap each other's stalls. id = qblk*16 + b, qblk in [0,32);
// WG covers 64 q-rows. Wave = (half = w>>2 over kv, qh = w&3 over 16-q strips).
// Per half: wave qh=0 stages K, qh=1 stages V (global_load_lds, triple-buffered,
// vmcnt(4) -- DMA queue never drains); ONE s_barrier per iter. P redistribution
// in-register (cvt_pk + permlane32/16_swap).
__global__ __launch_bounds__(512, 4) void attn_kernel(
        const unsigned short* __restrict__ Qb,
        const unsigned short* __restrict__ Kb,
        const unsigned short* __restrict__ Vt,
        float* __restrict__ out) {
    __shared__ union {
        unsigned char stg[2][3][8192];   // [half][buf][ K 4KB | V 4KB ]
        float accL[64][66];              // combine overlay
    } u;
    __shared__ float lL[2][64];

    int tid = threadIdx.x;
    int wave = tid >> 6, lane = tid & 63, quad = lane >> 4, l15 = lane & 15;
    int half = wave >> 2, qh = wave & 3;
    int id = blockIdx.x;
    int b = id & 15, qblk = id >> 4;          // XCD = b%8 (matches qkv writes)
    int q0 = qblk * 64 + qh * 16;
    int kbase = half * 1024;

    // Q fragment (B-operand of S^T): Q[q=l15][h=kh*32+quad*8+j]
    short8 qf[2];
    #pragma unroll
    for (int kh = 0; kh < 2; ++kh)
        qf[kh] = *(const short8*)&Qb[((size_t)(b * TT + q0 + l15)) * 64 + kh * 32 + quad * 8];

    floatx4 acc[4];
    float lpart = 0.f;
    #pragma unroll
    for (int hb = 0; hb < 4; ++hb) acc[hb] = (floatx4){0.f, 0.f, 0.f, 0.f};

    // stage tile `it` into buf p. K swizzle c'=c^(kv&7); V swizzle c'=c^((h>>1)&3).
    auto stage = [&](int it, int p) {
        int kt = kbase + it * 32;
        if (qh == 0) {
            unsigned char* base = u.stg[half][p];
            #pragma unroll
            for (int i = 0; i < 4; ++i) {
                int ci = i * 64 + lane;
                int kv = ci >> 3, cp = ci & 7, c = cp ^ (kv & 7);
                GLD16(Kb + ((size_t)(b * TT + kt + kv) * 64 + c * 8), base + i * 1024);
            }
        } else if (qh == 1) {
            unsigned char* base = u.stg[half][p] + 4096;
            #pragma unroll
            for (int i = 0; i < 4; ++i) {
                int ci = i * 64 + lane;
                int h = ci >> 2, cp = ci & 3, c = cp ^ ((h >> 1) & 3);
                GLD16(Vt + ((size_t)(b * 64 + h) * TT + kt + c * 8), base + i * 1024);
            }
        }
    };

    auto compute = [&](int p) {
        const unsigned char* Kbuf = u.stg[half][p];
        const unsigned char* Vbuf = Kbuf + 4096;

        short8 kf[2][2], vf[4];
        #pragma unroll
        for (int ks = 0; ks < 2; ++ks)
            #pragma unroll
            for (int kh = 0; kh < 2; ++kh) {
                int cp = (kh * 4 + quad) ^ (l15 & 7);
                kf[ks][kh] = *(const short8*)(Kbuf + (ks * 16 + l15) * 128 + cp * 16);
            }
        #pragma unroll
        for (int hb = 0; hb < 4; ++hb) {
            int cp = quad ^ ((l15 >> 1) & 3);
            vf[hb] = *(const short8*)(Vbuf + (hb * 16 + l15) * 64 + cp * 16);
        }

        floatx4 s[2];
        #pragma unroll
        for (int ks = 0; ks < 2; ++ks) {
            floatx4 z = (floatx4){0.f, 0.f, 0.f, 0.f};
            z = __builtin_amdgcn_mfma_f32_16x16x32_bf16(kf[ks][0], qf[0], z, 0, 0, 0);
            z = __builtin_amdgcn_mfma_f32_16x16x32_bf16(kf[ks][1], qf[1], z, 0, 0, 0);
            s[ks] = z;
        }

        // exp + pack: c[ks][d] = bf16pair(e[2d], e[2d+1]) at k=16ks+4quad+2d
        unsigned c00, c01, c10, c11;
        {
            float e0 = __builtin_amdgcn_exp2f(s[0][0]);
            float e1 = __builtin_amdgcn_exp2f(s[0][1]);
            float e2 = __builtin_amdgcn_exp2f(s[0][2]);
            float e3 = __builtin_amdgcn_exp2f(s[0][3]);
            lpart += (e0 + e1) + (e2 + e3);
            c00 = cvtpk(e0, e1); c01 = cvtpk(e2, e3);
        }
        {
            float e0 = __builtin_amdgcn_exp2f(s[1][0]);
            float e1 = __builtin_amdgcn_exp2f(s[1][1]);
            float e2 = __builtin_amdgcn_exp2f(s[1][2]);
            float e3 = __builtin_amdgcn_exp2f(s[1][3]);
            lpart += (e0 + e1) + (e2 + e3);
            c10 = cvtpk(e0, e1); c11 = cvtpk(e2, e3);
        }

        // in-register quad redistribution -> PV A-fragment
        asm("v_permlane32_swap_b32 %0, %1" : "+v"(c00), "+v"(c10));
        asm("v_permlane16_swap_b32 %0, %1" : "+v"(c00), "+v"(c10));  // c00=P0 c10=P2
        asm("v_permlane32_swap_b32 %0, %1" : "+v"(c01), "+v"(c11));
        asm("v_permlane16_swap_b32 %0, %1" : "+v"(c01), "+v"(c11));  // c01=P1 c11=P3

        union { short8 s8; unsigned w[4]; } pu;
        pu.w[0] = c00; pu.w[1] = c01; pu.w[2] = c10; pu.w[3] = c11;
        #pragma unroll
        for (int hb = 0; hb < 4; ++hb)
            acc[hb] = __builtin_amdgcn_mfma_f32_16x16x32_bf16(pu.s8, vf[hb], acc[hb], 0, 0, 0);
    };

    stage(0, 0);
    stage(1, 1);
    for (int it = 0; it < 32; ++it) {
        if (qh < 2) {
            if (it < 31) { WAITV4; } else { WAITV0; }   // tile `it` landed, it+1 in flight
        }
        BAR;                                            // tile visible WG-wide
        if (it + 2 < 32) stage(it + 2, (it + 2) % 3);   // overwrites buf read at it-1 (done)
        compute(it % 3);
    }

    // l: sum across quads -> row sums for q=l15
    {
        float v = lpart;
        v += __shfl_xor(v, 16);
        v += __shfl_xor(v, 32);
        if (quad == 0) lL[half][qh * 16 + l15] = v;
    }
    __syncthreads();   // full drain OK here (epilogue); lL visible

    if (half == 1) {
        #pragma unroll
        for (int hb = 0; hb < 4; ++hb)
            #pragma unroll
            for (int r = 0; r < 4; ++r)
                u.accL[qh * 16 + quad * 4 + r][hb * 16 + l15] = acc[hb][r];
    }
    __syncthreads();

    if (half == 0) {
        float rl[4];
        #pragma unroll
        for (int r = 0; r < 4; ++r) {
            int qw = qh * 16 + quad * 4 + r;
            rl[r] = 1.0f / (lL[0][qw] + lL[1][qw]);
        }
        #pragma unroll
        for (int hb = 0; hb < 4; ++hb)
            #pragma unroll
            for (int r = 0; r < 4; ++r) {
                int qw = qh * 16 + quad * 4 + r;
                float tot = acc[hb][r] + u.accL[qw][hb * 16 + l15];
                out[((size_t)(b * TT + qblk * 64 + qw)) * 64 + hb * 16 + l15] = tot * rl[r];
            }
    }
}

extern "C" void kernel_launch(void* const* d_in, const int* in_sizes, int n_in,
                              void* d_out, int out_size, void* d_ws, size_t ws_size,
                              hipStream_t stream) {
    const float* x  = (const float*)d_in[0];
    const float* Wk = (const float*)d_in[1];
    const float* Wq = (const float*)d_in[2];
    const float* Wv = (const float*)d_in[3];

    unsigned short* Qb = (unsigned short*)d_ws;
    unsigned short* Kb = Qb + (size_t)BB * TT * HH;
    unsigned short* Vt = Kb + (size_t)BB * TT * HH;
    unsigned short* Wt = Vt + (size_t)BB * TT * HH;
    float* out = (float*)d_out;

    prep_w<<<dim3(72), dim3(256), 0, stream>>>(Wk, Wq, Wv, Wt);
    qkv_kernel<<<dim3(BB * TT / 64), dim3(256), 0, stream>>>(x, Wt, Qb, Kb, Vt);
    attn_kernel<<<dim3(BB * (TT / 64)), dim3(512), 0, stream>>>(Qb, Kb, Vt, out);
}